// Round 9
// baseline (159.023 us; speedup 1.0000x reference)
//
#include <hip/hip_runtime.h>
#include <math.h>

#define NB 4
#define PP 256
#define CC 151
#define RR 51
#define CM 160                 // padded C (5 tiles of 32)
#define KS 32                  // split-K: 8 i's per block
#define NROW (NB*PP)           // 1024
#define RELTOT (NB*PP*PP*RR)   // 13,369,344 floats
#define MLB 10240              // halves per l in m-layout: 8 oct * 160 c * 8 j
#define PREPB (CC*2)           // 302 prep blocks

typedef _Float16 half8 __attribute__((ext_vector_type(8)));
typedef float floatx16 __attribute__((ext_vector_type(16)));
typedef float float4u __attribute__((ext_vector_type(4), aligned(4)));  // dword-aligned ok

// ws layout (bytes): m1g, m2g, part
#define OFF_M1 ((size_t)0)
#define OFF_M2 (OFF_M1 + (size_t)CC*MLB*2)        // +3,092,480
#define OFF_PT (OFF_M2 + (size_t)CC*MLB*2)        // part: 1024*32*160*4 = 21.0 MB

// ---------------------------------------------------------------------------
// K1: prep only (rel16 conversion ELIMINATED — r8 post-mortem: dwordx4 needs
// only 4-B alignment, so gemm reads rel f32 fragments directly in 2 instrs;
// the 87-MB conv round-trip was redundant).
// m1g[l][oct][c][j] = w_r * M[l][c][oct*8+j]   (r = oct*8+j)
// m2g[l][oct][c][j] = w_r * M[c][l][oct*8+j]
// w_0 = 0.5, w_{r>=1} = 0.25; zero for r >= 51 or c >= 151 (the zero
// r-columns are what make gemm's past-row-end A reads exact).
// ---------------------------------------------------------------------------
__global__ __launch_bounds__(256) void prep_kernel(const float* __restrict__ M,
                                                   _Float16* __restrict__ m1,
                                                   _Float16* __restrict__ m2,
                                                   float* __restrict__ out) {
    const int bid = blockIdx.x;
    const int l = (bid < CC) ? bid : bid - CC;   // 0..150
    const int mat = (bid < CC) ? 0 : 1;
    if (bid == 0 && threadIdx.x == 0) *out = 0.f;
    _Float16* dst = (mat ? m2 : m1) + (size_t)l * MLB;
    for (int e = threadIdx.x; e < MLB; e += 256) {
        int oct = e / 1280;
        int rem = e - oct * 1280;
        int c = rem >> 3, j = rem & 7;
        int r = oct * 8 + j;
        float v = 0.f;
        if (r < RR && c < CC) {
            size_t src = ((size_t)(mat ? c * CC + l : l * CC + c)) * RR + r;
            v = (r == 0 ? 0.5f : 0.25f) * M[src];
        }
        dst[e] = (_Float16)v;
    }
}

// ---------------------------------------------------------------------------
// K2 (fused transpose+GEMM, 32x32x16 MFMA) — counted-vmcnt ring-6 pipeline
// (r7/r8's verified T3+T4 structure), A read DIRECTLY from rel f32:
//   - per thread per step: EXACTLY 4 vmem ops — B slab 5120 B as one 16-B
//     DMA + one 4-B DMA, plus A = 2x global_load_dwordx4 (aligned(4) vector
//     type; dwordx4 needs only dword alignment). cvt f32->f16 at compute
//     (same RTN cvt the conv pass did -> bit-identical).
//   - A reads past row end (r-slots 51..63) land in the next row: finite
//     values x exactly-zero B columns = 0. Only the final diagonal element
//     can run off the buffer -> clamp (that row is dz-zeroed anyway).
//   - ring of 6 B-buffers, prefetch distance 3. Per step:
//       stage(h+3) -> s_waitcnt vmcnt(12) -> s_barrier -> 5x MFMA
//     vmcnt(12) retires exactly step h's {B,B,A,A}; h+1..h+3 in flight;
//     no vmcnt(0) drain in the loop. Tail: 8/4/0.
//   - each rel element is read by exactly 2 blocks (mh0/mh1 owners); rel
//     (53.5 MB) fits the 256-MB L3, so the second pass is L3-served.
// Grid 256 = 4 img x 2 rowblk x 32 ks; 64 K-steps (8 i x 2 mat x 4 t).
// ---------------------------------------------------------------------------
__global__ __launch_bounds__(256) void gemm_kernel(const float* __restrict__ rel,
                                                   const _Float16* __restrict__ m1,
                                                   const _Float16* __restrict__ m2,
                                                   const int* __restrict__ labels,
                                                   float* __restrict__ part) {
    __shared__ _Float16 Bt[6][2560];       // 6 x 5 KB = 30 KB
    const int tid  = threadIdx.x;
    const int ks   = blockIdx.x & 31;
    const int rbk  = (blockIdx.x >> 5) & 1;
    const int n    = blockIdx.x >> 6;
    const int wave = tid >> 6, lane = tid & 63;
    const int m32  = lane & 31, kh = lane >> 5;
    const int i0   = ks * 8;
    const int rowimg = rbk * 128 + wave * 32 + m32;   // this lane's A row (q, in-image)

    int labs[8];
    #pragma unroll
    for (int j = 0; j < 8; ++j) labs[j] = labels[n * PP + i0 + j];

    floatx16 acc[5];
    #pragma unroll
    for (int ct = 0; ct < 5; ++ct)
        #pragma unroll
        for (int r2 = 0; r2 < 16; ++r2) acc[ct][r2] = 0.f;

    float4u aF[4][2];                      // ring of 4 A-fragments (f32)

    // step h = (i_loc<<3) | (mat<<2) | t ; il 0..7, t = k16-step
    auto stageB = [&](int h, int buf) {
        const int il = h >> 3, mh = (h >> 2) & 1, t = h & 3;
        const _Float16* base = (mh ? m2 : m1) + (size_t)labs[il] * MLB + t * 2560;
        // 16-B chunk: threads cover halves [0,2048); uniform 1 op/thread
        __builtin_amdgcn_global_load_lds(
            (const __attribute__((address_space(1))) unsigned int*)(base + tid * 8),
            (__attribute__((address_space(3))) unsigned int*)(&Bt[buf][tid * 8]),
            16, 0, 0);
        // 4-B chunk: halves [2048,2560); uniform 1 op/thread
        __builtin_amdgcn_global_load_lds(
            (const __attribute__((address_space(1))) unsigned int*)(base + 2048 + tid * 2),
            (__attribute__((address_space(3))) unsigned int*)(&Bt[buf][2048 + tid * 2]),
            4, 0, 0);
    };
    auto loadA = [&](int h) {
        const int il = h >> 3, mh = (h >> 2) & 1, t = h & 3;
        const int i = i0 + il;
        const int r0 = t * 16 + kh * 8;
        int idx = mh ? ((n * PP + rowimg) * PP + i) * RR + r0
                     : ((n * PP + i) * PP + rowimg) * RR + r0;
        idx = min(idx, RELTOT - 8);    // only reachable on the final diagonal (dz-zeroed)
        const float* p = rel + idx;
        aF[h & 3][0] = *(const float4u*)(p);
        aF[h & 3][1] = *(const float4u*)(p + 4);
    };
    auto computeStep = [&](int h) {
        const int il = h >> 3;
        const bool dz = (i0 + il) == rowimg;   // diagonal i == q -> zero A row
        half8 a;
        #pragma unroll
        for (int j = 0; j < 4; ++j) {
            a[j]     = (_Float16)(dz ? 0.f : aF[h & 3][0][j]);
            a[j + 4] = (_Float16)(dz ? 0.f : aF[h & 3][1][j]);
        }
        // B-frag: n = m32 (+ct*32), k = kh*8+j -> chunk (kh*160 + ct*32 + m32)
        const _Float16* bb = &Bt[h % 6][(size_t)(kh * 160 + m32) * 8];
        #pragma unroll
        for (int ct = 0; ct < 5; ++ct) {
            half8 b = *(const half8*)(bb + ct * 256);
            acc[ct] = __builtin_amdgcn_mfma_f32_32x32x16_f16(a, b, acc[ct], 0, 0, 0);
        }
    };

    // prologue: steps 0,1,2 in flight (12 ops/thread)
    stageB(0, 0); loadA(0);
    stageB(1, 1); loadA(1);
    stageB(2, 2); loadA(2);

    #pragma unroll
    for (int h = 0; h < 64; ++h) {
        if (h + 3 < 64) { stageB(h + 3, (h + 3) % 6); loadA(h + 3); }
        // retire step h's {B DMA x2, A x2}; keep h+1..h+3 in flight (4 each)
        if (h <= 60)      asm volatile("s_waitcnt vmcnt(12)" ::: "memory");
        else if (h == 61) asm volatile("s_waitcnt vmcnt(8)"  ::: "memory");
        else if (h == 62) asm volatile("s_waitcnt vmcnt(4)"  ::: "memory");
        else              asm volatile("s_waitcnt vmcnt(0)"  ::: "memory");
        __builtin_amdgcn_s_barrier();
        computeStep(h);
    }

    // C/D 32x32 layout (m74/m101): col = m32, row = (reg&3) + 8*(reg>>2) + 4*kh
    // part layout: [row][ks][c] -> K3 reads a contiguous 20-KB panel per row.
    float* pb = part + ((size_t)(n * PP + rbk * 128 + wave * 32) * KS + ks) * CM;
    #pragma unroll
    for (int ct = 0; ct < 5; ++ct)
        #pragma unroll
        for (int reg = 0; reg < 16; ++reg) {
            int row = (reg & 3) + 8 * (reg >> 2) + 4 * kh;
            pb[(size_t)row * KS * CM + ct * 32 + m32] = acc[ct][reg];
        }
}

// ---------------------------------------------------------------------------
// K3: theta[row][c] = sum_ks part[row][ks][c]; loss = lse - theta[lab]; mean.
// part panel per row is contiguous (20 KB) -> streaming reads.
// ---------------------------------------------------------------------------
__global__ __launch_bounds__(256) void reduce_loss_kernel(const float* __restrict__ part,
                                                          const int* __restrict__ labels,
                                                          float* __restrict__ out) {
    __shared__ float th[CM];
    const int row = blockIdx.x;
    const int t = threadIdx.x;
    if (t < CM) {
        const float* p = part + (size_t)row * KS * CM + t;
        float s = 0.f;
        #pragma unroll
        for (int ks = 0; ks < KS; ++ks)
            s += p[ks * CM];
        th[t] = s;
    }
    __syncthreads();
    if (t < 64) {
        float v0 = (t < CC)       ? th[t]       : -INFINITY;
        float v1 = (t + 64 < CC)  ? th[t + 64]  : -INFINITY;
        float v2 = (t + 128 < CC) ? th[t + 128] : -INFINITY;
        float m = fmaxf(v0, fmaxf(v1, v2));
        #pragma unroll
        for (int o = 32; o > 0; o >>= 1) m = fmaxf(m, __shfl_xor(m, o, 64));
        float s = 0.f;
        if (t < CC)       s += expf(v0 - m);
        if (t + 64 < CC)  s += expf(v1 - m);
        if (t + 128 < CC) s += expf(v2 - m);
        #pragma unroll
        for (int o = 32; o > 0; o >>= 1) s += __shfl_xor(s, o, 64);
        if (t == 0) {
            atomicAdd(out, (m + logf(s) - th[labels[row]]) * (1.0f / NROW));
        }
    }
}

// ---------------------------------------------------------------------------
extern "C" void kernel_launch(void* const* d_in, const int* in_sizes, int n_in,
                              void* d_out, int out_size, void* d_ws, size_t ws_size,
                              hipStream_t stream) {
    // inputs: 0=roi_scores (unused), 1=rel_scores, 2=relationship_mat,
    //         3=roi_labels, 4=num_images (fixed B=4)
    const float* rel    = (const float*)d_in[1];
    const float* relmat = (const float*)d_in[2];
    const int*   labels = (const int*)d_in[3];
    float* out = (float*)d_out;
    char* ws = (char*)d_ws;

    _Float16* m1    = (_Float16*)(ws + OFF_M1);
    _Float16* m2    = (_Float16*)(ws + OFF_M2);
    float*    part  = (float*)(ws + OFF_PT);

    prep_kernel<<<PREPB, 256, 0, stream>>>(relmat, m1, m2, out);
    gemm_kernel<<<NB * 2 * KS, 256, 0, stream>>>(rel, m1, m2, labels, part);
    reduce_loss_kernel<<<NROW, 256, 0, stream>>>(part, labels, out);
}

// Round 10
// 148.367 us; speedup vs baseline: 1.0718x; 1.0718x over previous
//
#include <hip/hip_runtime.h>
#include <math.h>

#define NB 4
#define PP 256
#define CC 151
#define RR 51
#define CM 160                 // padded C (5 tiles of 32)
#define KS 32                  // split-K: 8 i's per block
#define NROW (NB*PP)           // 1024
#define MLB 10240              // halves per l in m-layout: 8 oct * 160 c * 8 j
#define NRELROW (NB*PP*PP)     // 262,144 rows of rel
#define CONVB (NRELROW/8)      // 32,768 conv blocks (8 rows each)
#define PREPB (CC*2)           // 302 prep blocks

typedef _Float16 half8 __attribute__((ext_vector_type(8)));
typedef _Float16 half2v __attribute__((ext_vector_type(2)));
typedef float floatx16 __attribute__((ext_vector_type(16)));

// ws layout (bytes): m1g, m2g, part, rel16
#define OFF_M1 ((size_t)0)
#define OFF_M2 (OFF_M1 + (size_t)CC*MLB*2)        // +3,092,480
#define OFF_PT (OFF_M2 + (size_t)CC*MLB*2)        // part: 1024*32*160*4 = 21.0 MB
#define OFF_R16 (OFF_PT + (size_t)NROW*KS*CM*4)   // rel16: 262144*64*2 = 33.5 MB

// ---------------------------------------------------------------------------
// K1 (fused): prep (blocks 0..301) + rel->f16 conversion (blocks 302..).
// WHY THE CONV PASS EXISTS (r9 falsified removing it): gemm's A access is a
// per-lane scatter; with rel's native f32 stride-51 rows each wave A-op
// touches ~2x the cache lines and pays the TA transaction cost TWICE (mh0 +
// mh1 owners) -> gemm 46 us. Converting once (coalesced read 53.5 MB +
// coalesced write 33.5 MB) into 128-B f16 rows makes gemm's A one dwordx4
// per step -> gemm ~13 us. Net win ~18 us.
// prep: m1g[l][oct][c][j] = w_r * M[l][c][oct*8+j]   (r = oct*8+j)
//       m2g[l][oct][c][j] = w_r * M[c][l][oct*8+j]
//       w_0 = 0.5, w_{r>=1} = 0.25; zero for r >= 51 or c >= 151.
// conv: rel16[row][h] = (h<51 && a!=b) ? (_Float16)rel[row*51+h] : 0
//       Diagonal (a==b) rows pre-zeroed (off_diag free in gemm).
// ---------------------------------------------------------------------------
__global__ __launch_bounds__(256) void prep_kernel(const float* __restrict__ M,
                                                   const float* __restrict__ rel,
                                                   _Float16* __restrict__ m1,
                                                   _Float16* __restrict__ m2,
                                                   _Float16* __restrict__ rel16,
                                                   float* __restrict__ out) {
    const int bid = blockIdx.x;
    if (bid < PREPB) {
        const int l = (bid < CC) ? bid : bid - CC;   // 0..150
        const int mat = (bid < CC) ? 0 : 1;
        if (bid == 0 && threadIdx.x == 0) *out = 0.f;
        _Float16* dst = (mat ? m2 : m1) + (size_t)l * MLB;
        for (int e = threadIdx.x; e < MLB; e += 256) {
            int oct = e / 1280;
            int rem = e - oct * 1280;
            int c = rem >> 3, j = rem & 7;
            int r = oct * 8 + j;
            float v = 0.f;
            if (r < RR && c < CC) {
                size_t src = ((size_t)(mat ? c * CC + l : l * CC + c)) * RR + r;
                v = (r == 0 ? 0.5f : 0.25f) * M[src];
            }
            dst[e] = (_Float16)v;
        }
    } else {
        // conversion: 8 rel-rows per block, thread t -> row row0+(t>>5),
        // halves h0=2*(t&31), h1=h0+1.
        const int t = threadIdx.x;
        const size_t row = (size_t)(bid - PREPB) * 8 + (t >> 5);
        const int d  = t & 31;
        const int h0 = 2 * d;
        const int a  = ((int)row >> 8) & 255;
        const int b  = (int)row & 255;
        const bool live = (a != b);
        const float* src = rel + row * RR;
        float v0 = (live && h0 < RR)     ? src[h0]     : 0.f;
        float v1 = (live && h0 + 1 < RR) ? src[h0 + 1] : 0.f;
        half2v p;
        p[0] = (_Float16)v0;
        p[1] = (_Float16)v1;
        *(half2v*)(rel16 + row * 64 + h0) = p;
    }
}

// ---------------------------------------------------------------------------
// K2 (fused transpose+GEMM, 32x32x16 MFMA) — counted-vmcnt pipeline,
// KS=32 / distance-3 / ring-6 (verified T3+T4 structure, best measured):
//   - per thread per step: EXACTLY 3 vmem ops — B slab 5120 B as one 16-B
//     DMA + one 4-B DMA per thread, plus one A dwordx4 (8 halves) of rel16.
//   - ring of 6 B-buffers (30 KB). Per step:
//       stage(h+3) -> s_waitcnt vmcnt(9) -> s_barrier -> 5x MFMA
//     vmcnt(9) retires exactly step h's {A,B}; h+1..h+3 stay in flight;
//     no vmcnt(0) drain in the loop. Tail: 6/3/0. WAR-safe: buffer
//     rewritten >=2 barriers after its last ds_read.
//   - A held in 4 rotating half8 regs (full unroll -> static indices).
// Grid 256 = 4 img x 2 rowblk x 32 ks; 64 K-steps (8 i x 2 mat x 4 t).
// ---------------------------------------------------------------------------
__global__ __launch_bounds__(256) void gemm_kernel(const _Float16* __restrict__ rel16,
                                                   const _Float16* __restrict__ m1,
                                                   const _Float16* __restrict__ m2,
                                                   const int* __restrict__ labels,
                                                   float* __restrict__ part) {
    __shared__ _Float16 Bt[6][2560];       // 6 x 5 KB = 30 KB
    const int tid  = threadIdx.x;
    const int ks   = blockIdx.x & 31;
    const int rbk  = (blockIdx.x >> 5) & 1;
    const int n    = blockIdx.x >> 6;
    const int wave = tid >> 6, lane = tid & 63;
    const int m32  = lane & 31, kh = lane >> 5;
    const int i0   = ks * 8;
    const int rowimg = rbk * 128 + wave * 32 + m32;   // this lane's A row (q, in-image)

    int labs[8];
    #pragma unroll
    for (int j = 0; j < 8; ++j) labs[j] = labels[n * PP + i0 + j];

    floatx16 acc[5];
    #pragma unroll
    for (int ct = 0; ct < 5; ++ct)
        #pragma unroll
        for (int r2 = 0; r2 < 16; ++r2) acc[ct][r2] = 0.f;

    half8 aS[4];

    // step h = (i_loc<<3) | (mat<<2) | t ; il 0..7, t = k16-step
    auto stageB = [&](int h, int buf) {
        const int il = h >> 3, mh = (h >> 2) & 1, t = h & 3;
        const _Float16* base = (mh ? m2 : m1) + (size_t)labs[il] * MLB + t * 2560;
        // 16-B chunk: threads cover halves [0,2048); uniform 1 op/thread
        __builtin_amdgcn_global_load_lds(
            (const __attribute__((address_space(1))) unsigned int*)(base + tid * 8),
            (__attribute__((address_space(3))) unsigned int*)(&Bt[buf][tid * 8]),
            16, 0, 0);
        // 4-B chunk: halves [2048,2560); uniform 1 op/thread
        __builtin_amdgcn_global_load_lds(
            (const __attribute__((address_space(1))) unsigned int*)(base + 2048 + tid * 2),
            (__attribute__((address_space(3))) unsigned int*)(&Bt[buf][2048 + tid * 2]),
            4, 0, 0);
    };
    auto loadA = [&](int h) {
        const int il = h >> 3, mh = (h >> 2) & 1, t = h & 3;
        const int i = i0 + il;
        const size_t row = mh ? ((size_t)(n * PP + rowimg) * PP + i)
                              : ((size_t)(n * PP + i) * PP + rowimg);
        aS[h & 3] = *(const half8*)(rel16 + row * 64 + t * 16 + kh * 8);  // 16-B aligned
    };
    auto computeStep = [&](int h) {
        // B-frag: n = m32 (+ct*32), k = kh*8+j -> chunk (kh*160 + ct*32 + m32)
        const _Float16* bb = &Bt[h % 6][(size_t)(kh * 160 + m32) * 8];
        #pragma unroll
        for (int ct = 0; ct < 5; ++ct) {
            half8 b = *(const half8*)(bb + ct * 256);
            acc[ct] = __builtin_amdgcn_mfma_f32_32x32x16_f16(aS[h & 3], b, acc[ct], 0, 0, 0);
        }
    };

    // prologue: steps 0,1,2 in flight (9 ops/thread)
    stageB(0, 0); loadA(0);
    stageB(1, 1); loadA(1);
    stageB(2, 2); loadA(2);

    #pragma unroll
    for (int h = 0; h < 64; ++h) {
        if (h + 3 < 64) { stageB(h + 3, (h + 3) % 6); loadA(h + 3); }
        // retire step h's {B DMA x2, A load}; keep h+1..h+3 in flight (3 each)
        if (h <= 60)      asm volatile("s_waitcnt vmcnt(9)" ::: "memory");
        else if (h == 61) asm volatile("s_waitcnt vmcnt(6)" ::: "memory");
        else if (h == 62) asm volatile("s_waitcnt vmcnt(3)" ::: "memory");
        else              asm volatile("s_waitcnt vmcnt(0)" ::: "memory");
        __builtin_amdgcn_s_barrier();
        computeStep(h);
    }

    // C/D 32x32 layout (m74/m101): col = m32, row = (reg&3) + 8*(reg>>2) + 4*kh
    // part layout: [row][ks][c] -> K3 reads a contiguous 20-KB panel per row.
    float* pb = part + ((size_t)(n * PP + rbk * 128 + wave * 32) * KS + ks) * CM;
    #pragma unroll
    for (int ct = 0; ct < 5; ++ct)
        #pragma unroll
        for (int reg = 0; reg < 16; ++reg) {
            int row = (reg & 3) + 8 * (reg >> 2) + 4 * kh;
            pb[(size_t)row * KS * CM + ct * 32 + m32] = acc[ct][reg];
        }
}

// ---------------------------------------------------------------------------
// K3: theta[row][c] = sum_ks part[row][ks][c]; loss = lse - theta[lab]; mean.
// part panel per row is contiguous (20 KB) -> streaming reads.
// ---------------------------------------------------------------------------
__global__ __launch_bounds__(256) void reduce_loss_kernel(const float* __restrict__ part,
                                                          const int* __restrict__ labels,
                                                          float* __restrict__ out) {
    __shared__ float th[CM];
    const int row = blockIdx.x;
    const int t = threadIdx.x;
    if (t < CM) {
        const float* p = part + (size_t)row * KS * CM + t;
        float s = 0.f;
        #pragma unroll
        for (int ks = 0; ks < KS; ++ks)
            s += p[ks * CM];
        th[t] = s;
    }
    __syncthreads();
    if (t < 64) {
        float v0 = (t < CC)       ? th[t]       : -INFINITY;
        float v1 = (t + 64 < CC)  ? th[t + 64]  : -INFINITY;
        float v2 = (t + 128 < CC) ? th[t + 128] : -INFINITY;
        float m = fmaxf(v0, fmaxf(v1, v2));
        #pragma unroll
        for (int o = 32; o > 0; o >>= 1) m = fmaxf(m, __shfl_xor(m, o, 64));
        float s = 0.f;
        if (t < CC)       s += expf(v0 - m);
        if (t + 64 < CC)  s += expf(v1 - m);
        if (t + 128 < CC) s += expf(v2 - m);
        #pragma unroll
        for (int o = 32; o > 0; o >>= 1) s += __shfl_xor(s, o, 64);
        if (t == 0) {
            atomicAdd(out, (m + logf(s) - th[labels[row]]) * (1.0f / NROW));
        }
    }
}

// ---------------------------------------------------------------------------
extern "C" void kernel_launch(void* const* d_in, const int* in_sizes, int n_in,
                              void* d_out, int out_size, void* d_ws, size_t ws_size,
                              hipStream_t stream) {
    // inputs: 0=roi_scores (unused), 1=rel_scores, 2=relationship_mat,
    //         3=roi_labels, 4=num_images (fixed B=4)
    const float* rel    = (const float*)d_in[1];
    const float* relmat = (const float*)d_in[2];
    const int*   labels = (const int*)d_in[3];
    float* out = (float*)d_out;
    char* ws = (char*)d_ws;

    _Float16* m1    = (_Float16*)(ws + OFF_M1);
    _Float16* m2    = (_Float16*)(ws + OFF_M2);
    float*    part  = (float*)(ws + OFF_PT);
    _Float16* rel16 = (_Float16*)(ws + OFF_R16);

    prep_kernel<<<PREPB + CONVB, 256, 0, stream>>>(relmat, rel, m1, m2, rel16, out);
    gemm_kernel<<<NB * 2 * KS, 256, 0, stream>>>(rel16, m1, m2, labels, part);
    reduce_loss_kernel<<<NROW, 256, 0, stream>>>(part, labels, out);
}